// Round 1
// baseline (252.401 us; speedup 1.0000x reference)
//
#include <hip/hip_runtime.h>

// LogSig depth-2: out[b] = concat(level1[32], areas[496])
//   M[i][j]  = sum_{l=0}^{L-2} x[b][l][i] * x[b][l+1][j]
//   A[i][j]  = 0.5*(M[i][j] - M[j][i] - x0[i]*L1[j] + x0[j]*L1[i])
//   (telescoped identity -- no cumsum materialization needed)

constexpr int kB   = 512;
constexpr int kL   = 2048;
constexpr int kD   = 32;
constexpr int kOut = 528;   // 32 level1 + 496 areas

__global__ __launch_bounds__(512, 4)
void logsig_kernel(const float* __restrict__ x, float* __restrict__ out) {
    __shared__ float sM[8 * 1024];   // per-wave partial M matrices (32 KB)
    __shared__ float sx0[32];
    __shared__ float sL1[32];

    const int b    = blockIdx.x;
    const int tid  = threadIdx.x;
    const int wave = tid >> 6;       // 8 waves
    const int lane = tid & 63;
    const int r    = lane >> 3;      // i-block 0..7  (rows 4r..4r+3)
    const int c    = lane & 7;       // j-block 0..7  (cols 4c..4c+3)

    const float* __restrict__ xb = x + (size_t)b * (kL * kD);

    // split the 2047 products into 8 chunks of 256 (last gets 255)
    const int per = 256;
    const int l0  = wave * per;
    const int l1  = (l0 + per < kL - 1) ? (l0 + per) : (kL - 1);
    const int n   = l1 - l0;

    float acc[4][4];
    #pragma unroll
    for (int a = 0; a < 4; ++a)
        #pragma unroll
        for (int q = 0; q < 4; ++q) acc[a][q] = 0.0f;

    const float* pi = xb + (size_t)l0 * kD + 4 * r;        // x[l][4r..4r+3]
    const float* pj = xb + (size_t)(l0 + 1) * kD + 4 * c;  // x[l+1][4c..4c+3]

    #pragma unroll 8
    for (int t = 0; t < n; ++t) {
        const float4 xi = *(const float4*)(pi + (size_t)t * kD);
        const float4 xj = *(const float4*)(pj + (size_t)t * kD);
        const float xiv[4] = {xi.x, xi.y, xi.z, xi.w};
        const float xjv[4] = {xj.x, xj.y, xj.z, xj.w};
        #pragma unroll
        for (int a = 0; a < 4; ++a)
            #pragma unroll
            for (int q = 0; q < 4; ++q)
                acc[a][q] += xiv[a] * xjv[q];
    }

    // dump per-wave 4x4 partial tiles into LDS
    {
        const int i0 = 4 * r, j0 = 4 * c;
        float* dst = sM + wave * 1024;
        #pragma unroll
        for (int a = 0; a < 4; ++a)
            #pragma unroll
            for (int q = 0; q < 4; ++q)
                dst[(i0 + a) * 32 + (j0 + q)] = acc[a][q];
    }
    __syncthreads();

    // reduce the 8 wave partials; each thread owns cells tid and tid+512,
    // reads/writes only its own cells -> no extra barrier needed before write
    for (int cell = tid; cell < 1024; cell += 512) {
        float s = 0.0f;
        #pragma unroll
        for (int w = 0; w < 8; ++w) s += sM[w * 1024 + cell];
        sM[cell] = s;
    }

    if (tid < 32) {
        const float x0v = xb[tid];
        const float xlv = xb[(size_t)(kL - 1) * kD + tid];
        sx0[tid] = x0v;
        sL1[tid] = xlv - x0v;
        out[(size_t)b * kOut + tid] = xlv - x0v;   // level1
    }
    __syncthreads();

    if (tid < 496) {
        // map pair index -> (i, j), triu order: (0,1)..(0,31),(1,2)..
        int p = tid, i = 0;
        while (p >= 31 - i) { p -= 31 - i; ++i; }
        const int j = i + 1 + p;
        const float v = 0.5f * (sM[i * 32 + j] - sM[j * 32 + i]
                                - sx0[i] * sL1[j] + sx0[j] * sL1[i]);
        out[(size_t)b * kOut + 32 + tid] = v;
    }
}

extern "C" void kernel_launch(void* const* d_in, const int* in_sizes, int n_in,
                              void* d_out, int out_size, void* d_ws, size_t ws_size,
                              hipStream_t stream) {
    const float* x = (const float*)d_in[0];
    float* out = (float*)d_out;
    logsig_kernel<<<dim3(kB), dim3(512), 0, stream>>>(x, out);
}

// Round 3
// 221.272 us; speedup vs baseline: 1.1407x; 1.1407x over previous
//
#include <hip/hip_runtime.h>

// LogSig depth-2, telescoped:
//   M[i][j] = sum_t x[t][i]*x[t+1][j],  t in [0, L-1)
//   A[i][j] = 0.5*(M[i][j]-M[j][i] - x0[i]*L1[j] + x0[j]*L1[i]),  L1 = x[L-1]-x[0]
// Areas are linear in M, so the t-range is split across kNCH blocks per batch,
// each atomicAdd-ing its antisymmetrized partial into out (pre-zeroed).

constexpr int kB     = 512;
constexpr int kL     = 2048;
constexpr int kD     = 32;
constexpr int kOut   = 528;            // 32 level1 + 496 areas
constexpr int kNCH   = 4;              // chunks per batch
constexpr int kTper  = 512;            // t's per chunk (last chunk: 511)

__global__ __launch_bounds__(256, 4)
void logsig_partial(const float* __restrict__ x, float* __restrict__ out) {
    __shared__ float sW[4][1024];      // per-wave partial M (16 KB)
    __shared__ float sM[1024];         // block partial M (4 KB)
    __shared__ float sx0[32];
    __shared__ float sL1[32];

    const int b     = blockIdx.x >> 2;
    const int chunk = blockIdx.x & 3;
    const int tid   = threadIdx.x;
    const int wave  = tid >> 6;        // 0..3
    const int lane  = tid & 63;
    const int q     = lane >> 4;       // t-offset within wave's group of 4
    const int sub   = lane & 15;
    const int i0    = (sub >> 2) * 8;  // rows i0..i0+7
    const int j0    = (sub & 3) * 8;   // cols j0..j0+7

    const float* __restrict__ xb = x + (size_t)b * (kL * kD);

    const int t0   = chunk * kTper;
    const int tend = (t0 + kTper < kL - 1) ? (t0 + kTper) : (kL - 1);

    float acc[8][8];
    #pragma unroll
    for (int a = 0; a < 8; ++a)
        #pragma unroll
        for (int c = 0; c < 8; ++c) acc[a][c] = 0.0f;

    // block covers 16 t's per iteration: 4 waves x 4 quarter-waves
    #pragma unroll 2
    for (int it = 0; it < kTper / 16; ++it) {
        const int t = t0 + it * 16 + wave * 4 + q;
        if (t < tend) {
            const float* row = xb + (size_t)t * kD;
            const float4 a0 = *(const float4*)(row + i0);
            const float4 a1 = *(const float4*)(row + i0 + 4);
            const float4 b0 = *(const float4*)(row + kD + j0);
            const float4 b1 = *(const float4*)(row + kD + j0 + 4);
            const float av[8] = {a0.x, a0.y, a0.z, a0.w, a1.x, a1.y, a1.z, a1.w};
            const float bv[8] = {b0.x, b0.y, b0.z, b0.w, b1.x, b1.y, b1.z, b1.w};
            #pragma unroll
            for (int a = 0; a < 8; ++a)
                #pragma unroll
                for (int c = 0; c < 8; ++c)
                    acc[a][c] += av[a] * bv[c];
        }
    }

    // reduce across the 4 quarter-waves (lanes differing in bits 4,5)
    #pragma unroll
    for (int a = 0; a < 8; ++a)
        #pragma unroll
        for (int c = 0; c < 8; ++c) {
            float v = acc[a][c];
            v += __shfl_xor(v, 16, 64);
            v += __shfl_xor(v, 32, 64);
            acc[a][c] = v;
        }

    if (lane < 16) {
        #pragma unroll
        for (int a = 0; a < 8; ++a)
            #pragma unroll
            for (int c = 0; c < 8; ++c)
                sW[wave][(i0 + a) * 32 + (j0 + c)] = acc[a][c];
    }

    if (tid < 32) {
        const float x0v = xb[tid];
        sx0[tid] = x0v;
        sL1[tid] = xb[(size_t)(kL - 1) * kD + tid] - x0v;
    }
    __syncthreads();

    for (int cell = tid; cell < 1024; cell += 256)
        sM[cell] = sW[0][cell] + sW[1][cell] + sW[2][cell] + sW[3][cell];
    __syncthreads();

    float* ob = out + (size_t)b * kOut;
    // 528 outputs handled by 256 threads (stride loop!)
    for (int o = tid; o < kOut; o += 256) {
        if (o < 32) {
            if (chunk == 0) ob[o] = sL1[o];          // level1, single writer
        } else {
            int p = o - 32, i = 0;                   // triu pair index -> (i,j)
            while (p >= 31 - i) { p -= 31 - i; ++i; }
            const int j = i + 1 + p;
            float v = 0.5f * (sM[i * 32 + j] - sM[j * 32 + i]);
            if (chunk == 0)
                v += 0.5f * (sx0[j] * sL1[i] - sx0[i] * sL1[j]);
            atomicAdd(ob + o, v);
        }
    }
}

extern "C" void kernel_launch(void* const* d_in, const int* in_sizes, int n_in,
                              void* d_out, int out_size, void* d_ws, size_t ws_size,
                              hipStream_t stream) {
    const float* x = (const float*)d_in[0];
    float* out = (float*)d_out;
    hipMemsetAsync(out, 0, (size_t)out_size * sizeof(float), stream);
    logsig_partial<<<dim3(kB * kNCH), dim3(256), 0, stream>>>(x, out);
}

// Round 4
// 210.374 us; speedup vs baseline: 1.1998x; 1.0518x over previous
//
#include <hip/hip_runtime.h>
#include <stdint.h>

// LogSig depth-2 via MFMA: per batch, M = X0^T * X1 (32x32, K=2047), then
// A = 0.5*(M - M^T - x0 (x) L1 + L1 (x) x0),  L1 = x[L-1]-x[0].
// fp32 -> bf16 hi+lo split; M = aH*bH + aH*bL + aL*bH (fp32 MFMA accum).
// K padded to 2048 with a clamped row: bogus term x[2047](x)x[2047] is
// symmetric -> cancels exactly in the antisymmetrization.

constexpr int kB     = 512;
constexpr int kL     = 2048;
constexpr int kD     = 32;
constexpr int kOut   = 528;   // 32 level1 + 496 areas
constexpr int kTw    = 256;   // timesteps per wave (2 blocks x 4 waves per batch)
constexpr int kPan   = 32;    // timesteps per staged panel (one K=32 step)
constexpr int kSlot  = 36;    // padded dword slots per channel row (33 used)

typedef __attribute__((ext_vector_type(8))) short bfrag;   // 8 bf16 = 4 VGPR
typedef __attribute__((ext_vector_type(4))) float f4acc;

union FragU { uint32_t u[4]; bfrag f; };

__device__ __forceinline__ uint32_t bf16_rne(float f) {
    uint32_t fb = __builtin_bit_cast(uint32_t, f);
    return (fb + 0x7fffu + ((fb >> 16) & 1u)) >> 16;
}

__global__ __launch_bounds__(256, 4)
void logsig_mfma(const float* __restrict__ x, float* __restrict__ out) {
    __shared__ __align__(16) uint32_t xp[4][kD * kSlot];  // wave-private packed planes
    __shared__ float sM[kD * kD];
    __shared__ float sx0[kD], sL1[kD];

    const int b     = blockIdx.x >> 1;
    const int halfc = blockIdx.x & 1;
    const int tid   = threadIdx.x;
    const int wave  = tid >> 6;
    const int lane  = tid & 63;

    const float* __restrict__ xb = x + (size_t)b * (kL * kD);
    const int t0 = (halfc * 4 + wave) * kTw;

    uint32_t* wbuf = &xp[wave][0];

    // staging: sweep of 8 rows x 128B; lane -> (row=lane>>3, dword d0=(lane&7)*4)
    const int srow = lane >> 3;
    const int sd0  = (lane & 7) * 4;

    f4acc acc[4];   // tiles: acc[2*r+c] = A_r * B_c (16x16 each)
    #pragma unroll
    for (int t = 0; t < 4; ++t)
        #pragma unroll
        for (int e = 0; e < 4; ++e) acc[t][e] = 0.0f;

    auto load_panel = [&](int p, float4* G) {
        #pragma unroll
        for (int s = 0; s < 5; ++s) {
            const int r = s * 8 + srow;            // 0..39, valid < 33
            int row = t0 + p * kPan + r;
            row = row < kL - 1 ? row : kL - 1;     // clamp: halo + bogus-t
            if (r < 33)
                G[s] = *(const float4*)(xb + (size_t)row * kD + sd0);
        }
    };

    auto store_panel = [&](const float4* G) {
        #pragma unroll
        for (int s = 0; s < 5; ++s) {
            const int r = s * 8 + srow;
            if (r < 33) {
                const float v[4] = {G[s].x, G[s].y, G[s].z, G[s].w};
                #pragma unroll
                for (int k = 0; k < 4; ++k) {
                    const float f = v[k];
                    const uint32_t hi = bf16_rne(f);
                    const float fh = __builtin_bit_cast(float, hi << 16);
                    const uint32_t lo = bf16_rne(f - fh);
                    wbuf[(sd0 + k) * kSlot + r] = (hi & 0xffffu) | (lo << 16);
                }
            }
        }
    };

    const int m = lane & 15;    // MFMA m/n index
    const int q = lane >> 4;    // quad: k = q*8 + j

    auto panel_compute = [&](void) {
        const uint32_t* r0 = wbuf + m * kSlot + q * 8;          // A0/B0: channels 0..15
        const uint32_t* r1 = wbuf + (m + 16) * kSlot + q * 8;   // A1/B1: channels 16..31
        const uint4 a0l = *(const uint4*)(r0);
        const uint4 a0h = *(const uint4*)(r0 + 4);
        const uint4 a1l = *(const uint4*)(r1);
        const uint4 a1h = *(const uint4*)(r1 + 4);
        const uint32_t a0[8] = {a0l.x, a0l.y, a0l.z, a0l.w, a0h.x, a0h.y, a0h.z, a0h.w};
        const uint32_t a1[8] = {a1l.x, a1l.y, a1l.z, a1l.w, a1h.x, a1h.y, a1h.z, a1h.w};
        uint32_t b0[8], b1[8];                                   // +1 slot shift (B = x[t+1])
        #pragma unroll
        for (int j = 0; j < 8; ++j) { b0[j] = r0[j + 1]; b1[j] = r1[j + 1]; }

        FragU A0H, A0L, A1H, A1L, B0H, B0L, B1H, B1L;
        #pragma unroll
        for (int j = 0; j < 4; ++j) {
            A0H.u[j] = __builtin_amdgcn_perm(a0[2*j+1], a0[2*j], 0x05040100u);
            A0L.u[j] = __builtin_amdgcn_perm(a0[2*j+1], a0[2*j], 0x07060302u);
            A1H.u[j] = __builtin_amdgcn_perm(a1[2*j+1], a1[2*j], 0x05040100u);
            A1L.u[j] = __builtin_amdgcn_perm(a1[2*j+1], a1[2*j], 0x07060302u);
            B0H.u[j] = __builtin_amdgcn_perm(b0[2*j+1], b0[2*j], 0x05040100u);
            B0L.u[j] = __builtin_amdgcn_perm(b0[2*j+1], b0[2*j], 0x07060302u);
            B1H.u[j] = __builtin_amdgcn_perm(b1[2*j+1], b1[2*j], 0x05040100u);
            B1L.u[j] = __builtin_amdgcn_perm(b1[2*j+1], b1[2*j], 0x07060302u);
        }
        // acc[2r+c] += A_r * B_c, three precision passes each
        acc[0] = __builtin_amdgcn_mfma_f32_16x16x32_bf16(A0H.f, B0H.f, acc[0], 0, 0, 0);
        acc[0] = __builtin_amdgcn_mfma_f32_16x16x32_bf16(A0H.f, B0L.f, acc[0], 0, 0, 0);
        acc[0] = __builtin_amdgcn_mfma_f32_16x16x32_bf16(A0L.f, B0H.f, acc[0], 0, 0, 0);
        acc[1] = __builtin_amdgcn_mfma_f32_16x16x32_bf16(A0H.f, B1H.f, acc[1], 0, 0, 0);
        acc[1] = __builtin_amdgcn_mfma_f32_16x16x32_bf16(A0H.f, B1L.f, acc[1], 0, 0, 0);
        acc[1] = __builtin_amdgcn_mfma_f32_16x16x32_bf16(A0L.f, B1H.f, acc[1], 0, 0, 0);
        acc[2] = __builtin_amdgcn_mfma_f32_16x16x32_bf16(A1H.f, B0H.f, acc[2], 0, 0, 0);
        acc[2] = __builtin_amdgcn_mfma_f32_16x16x32_bf16(A1H.f, B0L.f, acc[2], 0, 0, 0);
        acc[2] = __builtin_amdgcn_mfma_f32_16x16x32_bf16(A1L.f, B0H.f, acc[2], 0, 0, 0);
        acc[3] = __builtin_amdgcn_mfma_f32_16x16x32_bf16(A1H.f, B1H.f, acc[3], 0, 0, 0);
        acc[3] = __builtin_amdgcn_mfma_f32_16x16x32_bf16(A1H.f, B1L.f, acc[3], 0, 0, 0);
        acc[3] = __builtin_amdgcn_mfma_f32_16x16x32_bf16(A1L.f, B1H.f, acc[3], 0, 0, 0);
    };

    // ---- pipelined main loop: prefetch panel p+1 while computing panel p ----
    float4 G[5];
    load_panel(0, G);
    store_panel(G);
    for (int p = 0; p < kTw / kPan; ++p) {
        float4 Gn[5];
        if (p < kTw / kPan - 1) load_panel(p + 1, Gn);
        panel_compute();                       // in-wave LDS ordering: reads before
        if (p < kTw / kPan - 1) store_panel(Gn);  // next panel's writes
    }

    // ---- epilogue: cross-wave reduce via LDS, antisymmetrize, atomic to out ----
    for (int c = tid; c < kD * kD; c += 256) sM[c] = 0.0f;
    if (tid < kD) {
        const float x0v = xb[tid];
        const float xev = xb[(size_t)(kL - 1) * kD + tid];
        sx0[tid] = x0v;
        sL1[tid] = xev - x0v;
    }
    __syncthreads();

    #pragma unroll
    for (int t = 0; t < 4; ++t) {
        const int tr = t >> 1, tc = t & 1;
        #pragma unroll
        for (int e = 0; e < 4; ++e) {
            const int row = 16 * tr + q * 4 + e;   // C/D layout (m89-verified)
            const int col = 16 * tc + m;
            atomicAdd(&sM[row * kD + col], acc[t][e]);
        }
    }
    __syncthreads();

    float* ob = out + (size_t)b * kOut;
    for (int o = tid; o < kOut; o += 256) {
        if (o < 32) {
            if (halfc == 0) ob[o] = sL1[o];        // level1, single writer
        } else {
            int p = o - 32, i = 0;                 // triu pair index -> (i,j)
            while (p >= 31 - i) { p -= 31 - i; ++i; }
            const int j = i + 1 + p;
            float v = 0.5f * (sM[i * kD + j] - sM[j * kD + i]);
            if (halfc == 0)
                v += 0.5f * (sx0[j] * sL1[i] - sx0[i] * sL1[j]);
            atomicAdd(ob + o, v);
        }
    }
}

extern "C" void kernel_launch(void* const* d_in, const int* in_sizes, int n_in,
                              void* d_out, int out_size, void* d_ws, size_t ws_size,
                              hipStream_t stream) {
    const float* x = (const float*)d_in[0];
    float* out = (float*)d_out;
    hipMemsetAsync(out, 0, (size_t)out_size * sizeof(float), stream);
    logsig_mfma<<<dim3(kB * 2), dim3(256), 0, stream>>>(x, out);
}

// Round 5
// 208.598 us; speedup vs baseline: 1.2100x; 1.0085x over previous
//
#include <hip/hip_runtime.h>
#include <stdint.h>

// LogSig depth-2 via MFMA, LDS-free main loop.
//   M = sum_t x[t] (x) x[t+1]  (32x32, K eff 2047, padded to 2048 with a
//   clamped row whose bogus symmetric term cancels in antisymmetrization)
//   A = 0.5*(M - M^T - x0 (x) L1 + L1 (x) x0),  L1 = x[L-1]-x[0]
// fp32 -> bf16 truncation split (hi = top 16 bits, lo = bf16(a - hi)):
//   M ~= aH*bH + aH*bL + aL*bH, dropped terms ~2^-16 -- fp32-level accuracy.
// A-fragment loaded straight from global: lane(m=lane&15, q=lane>>4) reads
// x[t0p + q*8 + j][m] -- 4 rows x 16 contiguous dwords per wave instruction.
// B chain = A chain shifted by one timestep in the SAME lane: only 1 extra
// load per 8. No LDS staging, no barriers in the main loop.

constexpr int kB   = 512;
constexpr int kL   = 2048;
constexpr int kD   = 32;
constexpr int kOut = 528;          // 32 level1 + 496 areas
constexpr int kTw  = 256;          // timesteps per wave (2 blocks x 4 waves/batch)
constexpr int kPan = 32;           // timesteps per panel (one K=32 MFMA step)
constexpr int kNP  = kTw / kPan;   // 8 panels per wave

typedef __attribute__((ext_vector_type(8))) short bfrag;   // 8 bf16 = 4 VGPR
typedef __attribute__((ext_vector_type(4))) float f4acc;
union FragU { uint32_t u[4]; bfrag f; };

__global__ __launch_bounds__(256, 4)
void logsig_mfma(const float* __restrict__ x, float* __restrict__ out) {
    __shared__ float sM[kD * kD];
    __shared__ float sx0[kD], sL1[kD];

    const int b     = blockIdx.x >> 1;
    const int halfc = blockIdx.x & 1;
    const int tid   = threadIdx.x;
    const int wave  = tid >> 6;
    const int lane  = tid & 63;
    const int m     = lane & 15;   // MFMA m/n index
    const int q     = lane >> 4;   // quad: k = q*8 + j

    const float* __restrict__ xb = x + (size_t)b * (kL * kD);
    const int t0 = (halfc * 4 + wave) * kTw;
    const int rb0 = t0 + q * 8;    // per-lane base row, panel 0

    // chain base: &x[rb0][m]; panel p adds p*32 rows
    const uint32_t* __restrict__ base =
        (const uint32_t*)xb + (size_t)rb0 * kD + m;

    f4acc acc[4];
    #pragma unroll
    for (int t = 0; t < 4; ++t)
        #pragma unroll
        for (int e = 0; e < 4; ++e) acc[t][e] = 0.0f;

    // load 9-element chains for both channel halves (j=0..7 plus shifted extra)
    auto load_panel = [&](int p, uint32_t* e0, uint32_t* e1) {
        const uint32_t* bp = base + (size_t)p * kPan * kD;
        #pragma unroll
        for (int j = 0; j < 8; ++j) {
            e0[j] = bp[j * kD];        // x[rb+j][m]
            e1[j] = bp[j * kD + 16];   // x[rb+j][m+16]
        }
        const int rb = rb0 + p * kPan;
        const int ex = (rb + 8 <= kL - 1 ? 8 : (kL - 1) - rb) * kD;  // clamp tail
        e0[8] = bp[ex];
        e1[8] = bp[ex + 16];
    };

    // truncation hi/lo split + perm-pack into A (pairs j,j+1) and B (pairs j+1,j+2)
    auto make_frags = [&](const uint32_t* e, FragU& AH, FragU& AL,
                          FragU& BH, FragU& BL) {
        uint32_t l[9];
        #pragma unroll
        for (int j = 0; j < 9; ++j) {
            const uint32_t fh = e[j] & 0xffff0000u;
            const float r = __builtin_bit_cast(float, e[j])
                          - __builtin_bit_cast(float, fh);
            l[j] = __builtin_bit_cast(uint32_t, r);
        }
        #pragma unroll
        for (int d = 0; d < 4; ++d) {
            AH.u[d] = __builtin_amdgcn_perm(e[2*d+1], e[2*d],   0x07060302u);
            AL.u[d] = __builtin_amdgcn_perm(l[2*d+1], l[2*d],   0x07060302u);
            BH.u[d] = __builtin_amdgcn_perm(e[2*d+2], e[2*d+1], 0x07060302u);
            BL.u[d] = __builtin_amdgcn_perm(l[2*d+2], l[2*d+1], 0x07060302u);
        }
    };

    uint32_t cur0[9], cur1[9], nxt0[9], nxt1[9];
    load_panel(0, cur0, cur1);

    #pragma unroll
    for (int p = 0; p < kNP; ++p) {
        if (p + 1 < kNP) load_panel(p + 1, nxt0, nxt1);

        FragU A0H, A0L, B0H, B0L, A1H, A1L, B1H, B1L;
        make_frags(cur0, A0H, A0L, B0H, B0L);
        make_frags(cur1, A1H, A1L, B1H, B1L);

        acc[0] = __builtin_amdgcn_mfma_f32_16x16x32_bf16(A0H.f, B0H.f, acc[0], 0, 0, 0);
        acc[0] = __builtin_amdgcn_mfma_f32_16x16x32_bf16(A0H.f, B0L.f, acc[0], 0, 0, 0);
        acc[0] = __builtin_amdgcn_mfma_f32_16x16x32_bf16(A0L.f, B0H.f, acc[0], 0, 0, 0);
        acc[1] = __builtin_amdgcn_mfma_f32_16x16x32_bf16(A0H.f, B1H.f, acc[1], 0, 0, 0);
        acc[1] = __builtin_amdgcn_mfma_f32_16x16x32_bf16(A0H.f, B1L.f, acc[1], 0, 0, 0);
        acc[1] = __builtin_amdgcn_mfma_f32_16x16x32_bf16(A0L.f, B1H.f, acc[1], 0, 0, 0);
        acc[2] = __builtin_amdgcn_mfma_f32_16x16x32_bf16(A1H.f, B0H.f, acc[2], 0, 0, 0);
        acc[2] = __builtin_amdgcn_mfma_f32_16x16x32_bf16(A1H.f, B0L.f, acc[2], 0, 0, 0);
        acc[2] = __builtin_amdgcn_mfma_f32_16x16x32_bf16(A1L.f, B0H.f, acc[2], 0, 0, 0);
        acc[3] = __builtin_amdgcn_mfma_f32_16x16x32_bf16(A1H.f, B1H.f, acc[3], 0, 0, 0);
        acc[3] = __builtin_amdgcn_mfma_f32_16x16x32_bf16(A1H.f, B1L.f, acc[3], 0, 0, 0);
        acc[3] = __builtin_amdgcn_mfma_f32_16x16x32_bf16(A1L.f, B1H.f, acc[3], 0, 0, 0);

        #pragma unroll
        for (int j = 0; j < 9; ++j) { cur0[j] = nxt0[j]; cur1[j] = nxt1[j]; }
    }

    // ---- epilogue: cross-wave reduce via LDS, antisymmetrize, atomic to out ----
    for (int c = tid; c < kD * kD; c += 256) sM[c] = 0.0f;
    if (tid < kD) {
        const float x0v = xb[tid];
        const float xev = xb[(size_t)(kL - 1) * kD + tid];
        sx0[tid] = x0v;
        sL1[tid] = xev - x0v;
    }
    __syncthreads();

    #pragma unroll
    for (int t = 0; t < 4; ++t) {
        const int tr = t >> 1, tc = t & 1;
        #pragma unroll
        for (int e = 0; e < 4; ++e) {
            const int row = 16 * tr + q * 4 + e;   // C/D layout (m89-verified)
            const int col = 16 * tc + m;
            atomicAdd(&sM[row * kD + col], acc[t][e]);
        }
    }
    __syncthreads();

    float* ob = out + (size_t)b * kOut;
    for (int o = tid; o < kOut; o += 256) {
        if (o < 32) {
            if (halfc == 0) ob[o] = sL1[o];        // level1, single writer
        } else {
            int p = o - 32, i = 0;                 // triu pair index -> (i,j)
            while (p >= 31 - i) { p -= 31 - i; ++i; }
            const int j = i + 1 + p;
            float v = 0.5f * (sM[i * kD + j] - sM[j * kD + i]);
            if (halfc == 0)
                v += 0.5f * (sx0[j] * sL1[i] - sx0[i] * sL1[j]);
            atomicAdd(ob + o, v);
        }
    }
}

extern "C" void kernel_launch(void* const* d_in, const int* in_sizes, int n_in,
                              void* d_out, int out_size, void* d_ws, size_t ws_size,
                              hipStream_t stream) {
    const float* x = (const float*)d_in[0];
    float* out = (float*)d_out;
    hipMemsetAsync(out, 0, (size_t)out_size * sizeof(float), stream);
    logsig_mfma<<<dim3(kB * 2), dim3(256), 0, stream>>>(x, out);
}

// Round 6
// 191.622 us; speedup vs baseline: 1.3172x; 1.0886x over previous
//
#include <hip/hip_runtime.h>
#include <stdint.h>

// LogSig depth-2 via MFMA, LDS-free main loop, one block per batch.
//   M = sum_t x[t] (x) x[t+1]  (32x32, K=2047, padded to 2048 with a clamped
//   row whose bogus symmetric term cancels in antisymmetrization)
//   A = 0.5*(M - M^T - x0 (x) L1 + L1 (x) x0),  L1 = x[L-1]-x[0]
// fp32 -> bf16 truncation split (hi = top 16 bits, lo = bf16(a - hi)):
//   M ~= aH*bH + aH*bL + aL*bH  (fp32 MFMA accumulate).
// A-fragment loaded straight from global: lane(m=lane&15, q=lane>>4) reads
// x[t0 + 32p + 8q + j][m]; B chain = A chain shifted one timestep in-lane.
// launch_bounds(256,2): 256-VGPR budget -- peak live ~100 regs, NO spills
// (the R4/R5 plateau at ~75us is attributed to scratch spills under the
// previous 128-VGPR cap). Grid 512 = 2 blocks/CU at 2 waves/EU: one pass.

constexpr int kB   = 512;
constexpr int kL   = 2048;
constexpr int kD   = 32;
constexpr int kOut = 528;          // 32 level1 + 496 areas
constexpr int kTw  = 512;          // timesteps per wave (1 block x 4 waves/batch)
constexpr int kPan = 32;           // timesteps per panel (one K=32 MFMA step)
constexpr int kNP  = kTw / kPan;   // 16 panels per wave

typedef __attribute__((ext_vector_type(8))) short bfrag;   // 8 bf16 = 4 VGPR
typedef __attribute__((ext_vector_type(4))) float f4acc;
union FragU { uint32_t u[4]; bfrag f; };

__global__ __launch_bounds__(256, 2)
void logsig_mfma(const float* __restrict__ x, float* __restrict__ out) {
    __shared__ float sW[4][kD * kD];   // per-wave partial M (16 KB)
    __shared__ float sM[kD * kD];
    __shared__ float sx0[kD], sL1[kD];

    const int b    = blockIdx.x;
    const int tid  = threadIdx.x;
    const int wave = tid >> 6;
    const int lane = tid & 63;
    const int m    = lane & 15;    // MFMA m/n index
    const int q    = lane >> 4;    // quad: k = q*8 + j

    const float* __restrict__ xb = x + (size_t)b * (kL * kD);
    const int t0  = wave * kTw;
    const int rb0 = t0 + q * 8;    // per-lane base row, panel 0

    const uint32_t* __restrict__ base =
        (const uint32_t*)xb + (size_t)rb0 * kD + m;

    f4acc acc[4];
    #pragma unroll
    for (int t = 0; t < 4; ++t)
        #pragma unroll
        for (int e = 0; e < 4; ++e) acc[t][e] = 0.0f;

    // 9-element chains (j=0..7 + one halo for the B shift), both channel halves
    auto load_panel = [&](int p, uint32_t* e0, uint32_t* e1) {
        const uint32_t* bp = base + (size_t)p * kPan * kD;
        #pragma unroll
        for (int j = 0; j < 8; ++j) {
            e0[j] = bp[j * kD];        // x[rb+j][m]
            e1[j] = bp[j * kD + 16];   // x[rb+j][m+16]
        }
        const int rb = rb0 + p * kPan;
        const int ex = (rb + 8 <= kL - 1 ? 8 : (kL - 1) - rb) * kD;  // end clamp
        e0[8] = bp[ex];
        e1[8] = bp[ex + 16];
    };

    // truncation hi/lo split + perm-pack: A pairs (j,j+1), B pairs (j+1,j+2)
    auto make_frags = [&](const uint32_t* e, FragU& AH, FragU& AL,
                          FragU& BH, FragU& BL) {
        uint32_t l[9];
        #pragma unroll
        for (int j = 0; j < 9; ++j) {
            const uint32_t fh = e[j] & 0xffff0000u;
            const float r = __builtin_bit_cast(float, e[j])
                          - __builtin_bit_cast(float, fh);
            l[j] = __builtin_bit_cast(uint32_t, r);
        }
        #pragma unroll
        for (int d = 0; d < 4; ++d) {
            AH.u[d] = __builtin_amdgcn_perm(e[2*d+1], e[2*d],   0x07060302u);
            AL.u[d] = __builtin_amdgcn_perm(l[2*d+1], l[2*d],   0x07060302u);
            BH.u[d] = __builtin_amdgcn_perm(e[2*d+2], e[2*d+1], 0x07060302u);
            BL.u[d] = __builtin_amdgcn_perm(l[2*d+2], l[2*d+1], 0x07060302u);
        }
    };

    uint32_t buf[2][2][9];   // [parity][half][chain]
    load_panel(0, buf[0][0], buf[0][1]);

    #pragma unroll 2
    for (int p = 0; p < kNP; ++p) {
        const int cu = p & 1, nx = cu ^ 1;
        if (p + 1 < kNP) load_panel(p + 1, buf[nx][0], buf[nx][1]);

        FragU A0H, A0L, B0H, B0L, A1H, A1L, B1H, B1L;
        make_frags(buf[cu][0], A0H, A0L, B0H, B0L);
        make_frags(buf[cu][1], A1H, A1L, B1H, B1L);

        acc[0] = __builtin_amdgcn_mfma_f32_16x16x32_bf16(A0H.f, B0H.f, acc[0], 0, 0, 0);
        acc[0] = __builtin_amdgcn_mfma_f32_16x16x32_bf16(A0H.f, B0L.f, acc[0], 0, 0, 0);
        acc[0] = __builtin_amdgcn_mfma_f32_16x16x32_bf16(A0L.f, B0H.f, acc[0], 0, 0, 0);
        acc[1] = __builtin_amdgcn_mfma_f32_16x16x32_bf16(A0H.f, B1H.f, acc[1], 0, 0, 0);
        acc[1] = __builtin_amdgcn_mfma_f32_16x16x32_bf16(A0H.f, B1L.f, acc[1], 0, 0, 0);
        acc[1] = __builtin_amdgcn_mfma_f32_16x16x32_bf16(A0L.f, B1H.f, acc[1], 0, 0, 0);
        acc[2] = __builtin_amdgcn_mfma_f32_16x16x32_bf16(A1H.f, B0H.f, acc[2], 0, 0, 0);
        acc[2] = __builtin_amdgcn_mfma_f32_16x16x32_bf16(A1H.f, B0L.f, acc[2], 0, 0, 0);
        acc[2] = __builtin_amdgcn_mfma_f32_16x16x32_bf16(A1L.f, B0H.f, acc[2], 0, 0, 0);
        acc[3] = __builtin_amdgcn_mfma_f32_16x16x32_bf16(A1H.f, B1H.f, acc[3], 0, 0, 0);
        acc[3] = __builtin_amdgcn_mfma_f32_16x16x32_bf16(A1H.f, B1L.f, acc[3], 0, 0, 0);
        acc[3] = __builtin_amdgcn_mfma_f32_16x16x32_bf16(A1L.f, B1H.f, acc[3], 0, 0, 0);
    }

    // ---- epilogue: per-wave plain stores (each lane owns 16 distinct cells),
    //      cross-wave sum, antisymmetrize, single-writer stores ----
    #pragma unroll
    for (int t = 0; t < 4; ++t) {
        const int tr = t >> 1, tc = t & 1;
        #pragma unroll
        for (int e = 0; e < 4; ++e) {
            const int row = 16 * tr + q * 4 + e;   // C/D layout (m89-verified)
            const int col = 16 * tc + m;
            sW[wave][row * kD + col] = acc[t][e];
        }
    }
    if (tid < kD) {
        const float x0v = xb[tid];
        const float xev = xb[(size_t)(kL - 1) * kD + tid];
        sx0[tid] = x0v;
        sL1[tid] = xev - x0v;
    }
    __syncthreads();

    for (int c = tid; c < kD * kD; c += 256)
        sM[c] = sW[0][c] + sW[1][c] + sW[2][c] + sW[3][c];
    __syncthreads();

    float* ob = out + (size_t)b * kOut;
    for (int o = tid; o < kOut; o += 256) {
        if (o < 32) {
            ob[o] = sL1[o];                        // level1
        } else {
            int p = o - 32, i = 0;                 // triu pair index -> (i,j)
            while (p >= 31 - i) { p -= 31 - i; ++i; }
            const int j = i + 1 + p;
            ob[o] = 0.5f * (sM[i * kD + j] - sM[j * kD + i]
                            + sx0[j] * sL1[i] - sx0[i] * sL1[j]);
        }
    }
}

extern "C" void kernel_launch(void* const* d_in, const int* in_sizes, int n_in,
                              void* d_out, int out_size, void* d_ws, size_t ws_size,
                              hipStream_t stream) {
    const float* x = (const float*)d_in[0];
    float* out = (float*)d_out;
    logsig_mfma<<<dim3(kB), dim3(256), 0, stream>>>(x, out);
}